// Round 6
// baseline (245.975 us; speedup 1.0000x reference)
//
#include <hip/hip_runtime.h>

constexpr int BLK = 256;

__device__ __forceinline__ void nerf_compute(
    float r, float th, float ph,
    float Ax, float Ay, float Az,
    float Bx, float By, float Bz,
    float Cx, float Cy, float Cz,
    float& Dx, float& Dy, float& Dz)
{
    float sth, cth, sph, cph;
    __sincosf(th, &sth, &cth);
    __sincosf(ph, &sph, &cph);
    float d0 = r * cth;
    float d1 = r * cph * sth;
    float d2 = r * sph * sth;

    float v1x = Bx - Ax, v1y = By - Ay, v1z = Bz - Az;
    float v2x = Cx - Bx, v2y = Cy - By, v2z = Cz - Bz;

    float inv2 = rsqrtf(v2x * v2x + v2y * v2y + v2z * v2z);
    float bcx = v2x * inv2, bcy = v2y * inv2, bcz = v2z * inv2;

    // n = normalize(cross(vec1, bc))
    float nx = v1y * bcz - v1z * bcy;
    float ny = v1z * bcx - v1x * bcz;
    float nz = v1x * bcy - v1y * bcx;
    float invn = rsqrtf(nx * nx + ny * ny + nz * nz);
    nx *= invn; ny *= invn; nz *= invn;

    // m = cross(n, bc)
    float mx = ny * bcz - nz * bcy;
    float my = nz * bcx - nx * bcz;
    float mz = nx * bcy - ny * bcx;

    Dx = d0 * bcx + d1 * mx + d2 * nx + Cx;
    Dy = d0 * bcy + d1 * my + d2 * ny + Cy;
    Dz = d0 * bcz + d1 * mz + d2 * nz + Cz;
}

__global__ __launch_bounds__(BLK) void nerf_kernel(
    const float* __restrict__ mc, const float* __restrict__ ic,
    float* __restrict__ out, int N)
{
    __shared__ float s_mc[BLK * 9];   // 9216 B
    __shared__ float s_ic[BLK * 3];   // 3072 B
    __shared__ float s_out[BLK * 3];  // 3072 B

    const int t = threadIdx.x;
    const long long base = (long long)blockIdx.x * BLK;
    const int rem = (int)(N - base);

    if (rem >= BLK) {
        // ---- fast path: full tile, cooperative float4 staging ----
        const float4* mc4 = reinterpret_cast<const float4*>(mc + base * 9);
        const float4* ic4 = reinterpret_cast<const float4*>(ic + base * 3);
        float4* s_mc4 = reinterpret_cast<float4*>(s_mc);
        float4* s_ic4 = reinterpret_cast<float4*>(s_ic);

        // 576 float4 of mainchain
        #pragma unroll
        for (int j = 0; j < 2; ++j)
            s_mc4[t + j * BLK] = mc4[t + j * BLK];
        if (t < (BLK * 9 / 4) - 2 * BLK)   // remaining 64
            s_mc4[t + 2 * BLK] = mc4[t + 2 * BLK];
        // 192 float4 of inner
        if (t < BLK * 3 / 4)
            s_ic4[t] = ic4[t];

        __syncthreads();

        float r  = s_ic[t * 3 + 0];
        float th = s_ic[t * 3 + 1];
        float ph = s_ic[t * 3 + 2];

        const float* e = &s_mc[t * 9];
        float Dx, Dy, Dz;
        nerf_compute(r, th, ph,
                     e[0], e[1], e[2],
                     e[3], e[4], e[5],
                     e[6], e[7], e[8],
                     Dx, Dy, Dz);

        s_out[t * 3 + 0] = Dx;
        s_out[t * 3 + 1] = Dy;
        s_out[t * 3 + 2] = Dz;

        __syncthreads();

        float4* o4 = reinterpret_cast<float4*>(out + base * 3);
        const float4* s_out4 = reinterpret_cast<const float4*>(s_out);
        if (t < BLK * 3 / 4)
            o4[t] = s_out4[t];
    } else {
        // ---- tail path (not hit for N divisible by 256, kept for safety) ----
        const long long i = base + t;
        if (i < (long long)N) {
            const float* e = mc + i * 9;
            float r  = ic[i * 3 + 0];
            float th = ic[i * 3 + 1];
            float ph = ic[i * 3 + 2];
            float Dx, Dy, Dz;
            nerf_compute(r, th, ph,
                         e[0], e[1], e[2],
                         e[3], e[4], e[5],
                         e[6], e[7], e[8],
                         Dx, Dy, Dz);
            out[i * 3 + 0] = Dx;
            out[i * 3 + 1] = Dy;
            out[i * 3 + 2] = Dz;
        }
    }
}

extern "C" void kernel_launch(void* const* d_in, const int* in_sizes, int n_in,
                              void* d_out, int out_size, void* d_ws, size_t ws_size,
                              hipStream_t stream) {
    const float* mc = (const float*)d_in[0];   // (3N, 3) float32
    const float* ic = (const float*)d_in[1];   // (N, 3)  float32
    float* out = (float*)d_out;                // (N, 3)  float32

    const int N = in_sizes[1] / 3;
    const int grid = (N + BLK - 1) / BLK;
    nerf_kernel<<<grid, BLK, 0, stream>>>(mc, ic, out, N);
}